// Round 3
// baseline (192.362 us; speedup 1.0000x reference)
//
#include <hip/hip_runtime.h>

#define T_ 4
#define B_ 8
#define N_ 1024
#define C_ 512
#define H_ 8
#define D_ 64
#define M_ (T_*B_*N_)   // 32768 rows
#define TB_ (T_*B_)     // 32

typedef __bf16 bf16;
typedef __bf16 bf16x4 __attribute__((ext_vector_type(4)));
typedef __bf16 bf16x8 __attribute__((ext_vector_type(8)));
typedef float f32x4 __attribute__((ext_vector_type(4)));

__device__ __forceinline__ void gload16(const void* g, void* l) {
  __builtin_amdgcn_global_load_lds(
      (const __attribute__((address_space(1))) void*)g,
      (__attribute__((address_space(3))) void*)l, 16, 0, 0);
}

// ---- fold BN into weights: W'[d,c] = W[d,c]*s[d], bias'[d] = (b-mu)*s + beta ----
__global__ void prep_w(const float* __restrict__ W, const float* __restrict__ b,
                       const float* __restrict__ g, const float* __restrict__ beta,
                       const float* __restrict__ mu, const float* __restrict__ var,
                       bf16* __restrict__ Wout, float* __restrict__ biasOut) {
  int d = blockIdx.x;
  float s = g[d] * rsqrtf(var[d] + 1e-5f);
  if (threadIdx.x == 0) biasOut[d] = (b[d] - mu[d]) * s + beta[d];
  for (int c = threadIdx.x; c < C_; c += blockDim.x)
    Wout[d * C_ + c] = (bf16)(W[d * C_ + c] * s);
}

// ---- WqT[c][d] = Wq[d][c] * sq[d]  (transposed folded Wq) ----
__global__ __launch_bounds__(256)
void prep_wqT(const float* __restrict__ W, const float* __restrict__ g,
              const float* __restrict__ var, bf16* __restrict__ WqT) {
  const int di = blockIdx.x >> 3, ci = blockIdx.x & 7;   // 8x8 tiles of 64x64
  const int t = threadIdx.x;
  __shared__ float lds[64][65];
  const int rgrp = t >> 4, k = t & 15;
#pragma unroll
  for (int p = 0; p < 4; p++) {
    int r = p * 16 + rgrp;
    int d = di * 64 + r;
    float s = g[d] * rsqrtf(var[d] + 1e-5f);
    float4 v = *(const float4*)(W + (size_t)d * 512 + ci * 64 + k * 4);
    lds[r][k*4+0] = v.x * s; lds[r][k*4+1] = v.y * s;
    lds[r][k*4+2] = v.z * s; lds[r][k*4+3] = v.w * s;
  }
  __syncthreads();
#pragma unroll
  for (int p = 0; p < 16; p++) {
    int c = p * 4 + (t >> 6), dd = t & 63;
    WqT[(size_t)(ci*64 + c) * 512 + di*64 + dd] = (bf16)lds[dd][c];
  }
}

// ---- x (f32) -> xb (bf16, [tb][n][c]) + xT (bf16, [tb][c][n]) + col-sum partials ----
__global__ __launch_bounds__(256)
void cvt_x_t(const float* __restrict__ x, bf16* __restrict__ xb,
             bf16* __restrict__ xT, float* __restrict__ spart) {
  const int bid = blockIdx.x;                       // tb*128 + nc*8 + cc
  const int tb = bid >> 7, nc = (bid >> 3) & 15, cc = bid & 7;
  const int t = threadIdx.x;
  __shared__ float lds[64][65];
  __shared__ float sred[16][64];
  const float* xbase = x + (size_t)tb * 524288 + (size_t)nc * 64 * 512 + cc * 64;
  bf16* xbb = xb + (size_t)tb * 524288 + (size_t)nc * 64 * 512 + cc * 64;
  bf16* xTb = xT + (size_t)tb * 524288 + (size_t)(cc * 64) * 1024 + nc * 64;
  const int rgrp = t >> 4, k = t & 15;
  float s0 = 0, s1 = 0, s2 = 0, s3 = 0;
#pragma unroll
  for (int p = 0; p < 4; p++) {
    int r = p * 16 + rgrp;
    float4 v = *(const float4*)(xbase + (size_t)r * 512 + k * 4);
    bf16x4 o; o[0]=(bf16)v.x; o[1]=(bf16)v.y; o[2]=(bf16)v.z; o[3]=(bf16)v.w;
    *(bf16x4*)(xbb + (size_t)r * 512 + k * 4) = o;
    lds[r][k*4+0]=v.x; lds[r][k*4+1]=v.y; lds[r][k*4+2]=v.z; lds[r][k*4+3]=v.w;
    s0 += v.x; s1 += v.y; s2 += v.z; s3 += v.w;
  }
  sred[rgrp][k*4+0]=s0; sred[rgrp][k*4+1]=s1; sred[rgrp][k*4+2]=s2; sred[rgrp][k*4+3]=s3;
  __syncthreads();
#pragma unroll
  for (int p = 0; p < 16; p++) {
    int c = p * 4 + (t >> 6), n = t & 63;
    xTb[(size_t)c * 1024 + n] = (bf16)lds[n][c];
  }
  if (t < 64) {
    float tot = 0;
#pragma unroll
    for (int rg = 0; rg < 16; rg++) tot += sred[rg][t];
    spart[(size_t)((tb*8 + cc)*16 + nc) * 64 + t] = tot;
  }
}

// ---- finalize column sums: s[tb][c] ----
__global__ __launch_bounds__(512)
void s_fin(const float* __restrict__ spart, float* __restrict__ sv) {
  const int tb = blockIdx.x, c = threadIdx.x;
  const int cc = c >> 6, cl = c & 63;
  float tot = 0;
#pragma unroll
  for (int ncf = 0; ncf < 16; ncf++)
    tot += spart[(size_t)((tb*8 + cc)*16 + ncf) * 64 + cl];
  sv[tb * 512 + c] = tot;
}

// ---- ks/vs: ksv[m][tb][d] = sum_c W'[m][d,c] * s[tb][c]  (m: 0=k,1=v) ----
__global__ __launch_bounds__(512)
void ksvs(const bf16* __restrict__ WB, const float* __restrict__ sv,
          float* __restrict__ ksv) {
  const int tb = blockIdx.x, m = blockIdx.y;
  __shared__ float sl[512];
  sl[threadIdx.x] = sv[tb * 512 + threadIdx.x];
  __syncthreads();
  const bf16* Wrow = WB + (size_t)(m + 1) * 262144 + (size_t)threadIdx.x * 512;
  float acc = 0;
  for (int c = 0; c < 512; c += 8) {
    bf16x8 wv = *(const bf16x8*)(Wrow + c);
#pragma unroll
    for (int i = 0; i < 8; i++) acc += (float)wv[i] * sl[c + i];
  }
  ksv[m * 16384 + tb * 512 + threadIdx.x] = acc;
}

// =====================================================================
// Batched 128x128-tile GEMM, BK=64, chunk-XOR swizzled LDS (conflict-free,
// verified round 2), gload_lds staging.  C[m][j] = sum_k A[m,k]*Bt[j,k].
// =====================================================================
template <int NKT, bool BF16OUT, bool HASBIAS>
__global__ __launch_bounds__(256)
void gemm_b(const bf16* __restrict__ Abase, size_t Astr,
            const bf16* __restrict__ Btbase, size_t Btstr,
            const float* __restrict__ biasb, int biasstr,
            bf16* __restrict__ ob, float* __restrict__ of, size_t Ostr,
            int ntiles) {
  constexpr int K = NKT * 64;
  const int bat = blockIdx.y;
  const bf16* A = Abase + (size_t)bat * Astr;
  const bf16* Bt = Btbase + (size_t)bat * Btstr;
  const int mi = blockIdx.x / ntiles, ni = blockIdx.x % ntiles;
  const int m0 = mi * 128, n0 = ni * 128;
  __shared__ __align__(16) bf16 As[128][64];
  __shared__ __align__(16) bf16 Bs[128][64];
  const int tid = threadIdx.x, w = tid >> 6, l = tid & 63;
  const int wm = w >> 1, wn = w & 1;
  const int lr = l & 15, lq = l >> 4, l7 = l & 7, lh = l >> 3;
  const int srcc = (l7 ^ lh) * 8;
  f32x4 acc[4][4] = {};
  for (int kt = 0; kt < NKT; kt++) {
#pragma unroll
    for (int i = 0; i < 4; i++) {
      int rb = w * 32 + i * 8;
      gload16(A  + (size_t)(m0 + rb + lh) * K + kt * 64 + srcc, &As[rb][0]);
      gload16(Bt + (size_t)(n0 + rb + lh) * K + kt * 64 + srcc, &Bs[rb][0]);
    }
    __syncthreads();
    bf16x8 af[4][2], bv[4][2];
#pragma unroll
    for (int f = 0; f < 4; f++) {
      int ra = wm * 64 + f * 16 + lr, rb2 = wn * 64 + f * 16 + lr;
#pragma unroll
      for (int s = 0; s < 2; s++) {
        af[f][s] = *(const bf16x8*)&As[ra][((s*4+lq) ^ (ra & 7)) * 8];
        bv[f][s] = *(const bf16x8*)&Bs[rb2][((s*4+lq) ^ (rb2 & 7)) * 8];
      }
    }
#pragma unroll
    for (int mt = 0; mt < 4; mt++)
#pragma unroll
      for (int nt = 0; nt < 4; nt++)
#pragma unroll
        for (int s = 0; s < 2; s++)
          acc[mt][nt] = __builtin_amdgcn_mfma_f32_16x16x32_bf16(
              af[mt][s], bv[nt][s], acc[mt][nt], 0, 0, 0);
    __syncthreads();
  }
  const int ldo = ntiles * 128;
#pragma unroll
  for (int mt = 0; mt < 4; mt++)
#pragma unroll
    for (int nt = 0; nt < 4; nt++) {
      int j = n0 + wn * 64 + nt * 16 + lr;
      float bj = HASBIAS ? biasb[(size_t)bat * biasstr + j] : 0.f;
      size_t mrow = (size_t)m0 + wm * 64 + mt * 16 + lq * 4;
#pragma unroll
      for (int r = 0; r < 4; r++) {
        if constexpr (BF16OUT)
          ob[(size_t)bat * Ostr + (mrow + r) * ldo + j] = (bf16)(acc[mt][nt][r] + bj);
        else
          of[(size_t)bat * Ostr + (mrow + r) * ldo + j] = acc[mt][nt][r] + bj;
      }
    }
}

// =====================================================================
// zchain: per (tb,h): KG = Kh*G ; kv = (KG*Vh^T + rank-1 bias terms)/N + bk bv^T
//         Z_h = kv * Ph^T ; write ZT[tb][j][64h+d]
// 4 waves, LDS: bufA 8K (Kh tile / kvb), bufV 64K (Vh), bufB 64K (G tile /
// KG slabs / f32 partials / Wp tile).  All tiles chunk-XOR swizzled.
// =====================================================================
__global__ __launch_bounds__(256)
void zchain(const bf16* __restrict__ Gb, const bf16* __restrict__ WB,
            const float* __restrict__ BS, const float* __restrict__ ksv,
            bf16* __restrict__ ZT) {
  const int gid = blockIdx.x, tb = gid >> 3, h = gid & 7;
  const int t = threadIdx.x, w = t >> 6, l = t & 63;
  const int lr = l & 15, lq = l >> 4, l7 = l & 7, lh = l >> 3;
  __shared__ __align__(16) char lds[8192 + 65536 + 65536];
  bf16* bufA = (bf16*)lds;                  // [64][64]
  bf16* bufV = (bf16*)(lds + 8192);         // [64][512]
  char* bufB = lds + 8192 + 65536;          // 64 KB
  const bf16* Gtb = Gb + (size_t)tb * 262144;

  // stage Vh: rows e (64), full 512 cols, swizzle chunk^ (e&7) over 64 chunks
#pragma unroll
  for (int ii = 0; ii < 16; ii++) {
    int e = w * 16 + ii;
    gload16(WB + 2u * 262144 + (size_t)(64*h + e) * 512 + ((l ^ (e & 7)) * 8),
            bufV + e * 512);
  }

  // ---- step1: KG[d, c'] = sum_c Kh[d,c] * G[c, c']  (G symmetric) ----
  f32x4 acc1[4][8] = {};
  for (int kt = 0; kt < 8; kt++) {
#pragma unroll
    for (int ii = 0; ii < 2; ii++) {
      int rb = w * 16 + ii * 8;
      gload16(WB + 1u * 262144 + (size_t)(64*h + rb + lh) * 512 + kt*64 + (l7 ^ lh) * 8,
              bufA + rb * 64);
    }
#pragma unroll
    for (int ii = 0; ii < 16; ii++) {
      int rb = w * 128 + ii * 8;
      gload16(Gtb + (size_t)(rb + lh) * 512 + kt*64 + (l7 ^ lh) * 8,
              (bf16*)bufB + rb * 64);
    }
    __syncthreads();
    bf16x8 af[4][2];
#pragma unroll
    for (int mf = 0; mf < 4; mf++) {
      int d = mf * 16 + lr;
#pragma unroll
      for (int s = 0; s < 2; s++)
        af[mf][s] = *(const bf16x8*)(bufA + d * 64 + (((s*4+lq) ^ (d & 7)) * 8));
    }
#pragma unroll
    for (int nf = 0; nf < 8; nf++) {
      int cp = w * 128 + nf * 16 + lr;
      bf16x8 bfv[2];
#pragma unroll
      for (int s = 0; s < 2; s++)
        bfv[s] = *(const bf16x8*)((bf16*)bufB + cp * 64 + (((s*4+lq) ^ (cp & 7)) * 8));
#pragma unroll
      for (int mf = 0; mf < 4; mf++)
#pragma unroll
        for (int s = 0; s < 2; s++)
          acc1[mf][nf] = __builtin_amdgcn_mfma_f32_16x16x32_bf16(
              af[mf][s], bfv[s], acc1[mf][nf], 0, 0, 0);
    }
    __syncthreads();
  }

  // ---- write KG (bf16) into per-wave slab [64][128], swizzled ----
  bf16* slab = (bf16*)bufB + w * 8192;
#pragma unroll
  for (int mf = 0; mf < 4; mf++)
#pragma unroll
    for (int nf = 0; nf < 8; nf++) {
      int cl = nf * 16 + lr;
      int ch = cl >> 3, co = cl & 7;
#pragma unroll
      for (int r = 0; r < 4; r++) {
        int d = mf * 16 + lq * 4 + r;
        slab[d * 128 + ((ch ^ (d & 7)) * 8 + co)] = (bf16)acc1[mf][nf][r];
      }
    }
  __syncthreads();

  // ---- step2: kv partial (this wave's K-slice of 128) ----
  f32x4 acc2[4][4] = {};
#pragma unroll
  for (int ks = 0; ks < 4; ks++) {
    bf16x8 af2[4], bv2[4];
#pragma unroll
    for (int mf = 0; mf < 4; mf++) {
      int d = mf * 16 + lr;
      af2[mf] = *(const bf16x8*)(slab + d * 128 + (((ks*4+lq) ^ (d & 7)) * 8));
    }
#pragma unroll
    for (int nf = 0; nf < 4; nf++) {
      int e = nf * 16 + lr;
      int gch = w * 16 + ks * 4 + lq;
      bv2[nf] = *(const bf16x8*)(bufV + e * 512 + ((gch ^ (e & 7)) * 8));
    }
#pragma unroll
    for (int mf = 0; mf < 4; mf++)
#pragma unroll
      for (int nf = 0; nf < 4; nf++)
        acc2[mf][nf] = __builtin_amdgcn_mfma_f32_16x16x32_bf16(
            af2[mf], bv2[nf], acc2[mf][nf], 0, 0, 0);
  }
  __syncthreads();   // all waves done reading KG slabs

  // ---- write f32 partials, reduce, add bias terms, kv -> bufA (bf16, swz) ----
  float* part = (float*)bufB + w * 4096;
#pragma unroll
  for (int mf = 0; mf < 4; mf++)
#pragma unroll
    for (int nf = 0; nf < 4; nf++)
#pragma unroll
      for (int r = 0; r < 4; r++) {
        int d = mf * 16 + lq * 4 + r, e = nf * 16 + lr;
        part[d * 64 + e] = acc2[mf][nf][r];
      }
  __syncthreads();
  {
    const float inv = 1.f / 1024.f;
    const float* pb = (const float*)bufB;
#pragma unroll
    for (int j = 0; j < 16; j++) {
      int flat = j * 256 + t, d = flat >> 6, e = flat & 63;
      float s = pb[flat] + pb[4096 + flat] + pb[8192 + flat] + pb[12288 + flat];
      float ksh = ksv[tb * 512 + 64*h + d];
      float vsh = ksv[16384 + tb * 512 + 64*h + e];
      float bkh = BS[512 + 64*h + d];
      float bvh = BS[1024 + 64*h + e];
      float kv = (s + ksh * bvh + bkh * vsh) * inv + bkh * bvh;
      bufA[d * 64 + (((e >> 3) ^ (d & 7)) * 8 + (e & 7))] = (bf16)kv;
    }
  }
  __syncthreads();

  // ---- stage Wp slice: Bt3[j][e] = Wp'[j][64h+e], 512 rows x 64 ----
#pragma unroll
  for (int ii = 0; ii < 16; ii++) {
    int rb = w * 128 + ii * 8;
    gload16(WB + 3u * 262144 + (size_t)(rb + lh) * 512 + 64*h + (l7 ^ lh) * 8,
            (bf16*)bufB + rb * 64);
  }
  __syncthreads();

  // ---- step3: Z_h = kv * Ph^T ; write ZT ----
  f32x4 acc3[4][8] = {};
#pragma unroll
  for (int s = 0; s < 2; s++) {
    bf16x8 af3[4];
#pragma unroll
    for (int mf = 0; mf < 4; mf++) {
      int d = mf * 16 + lr;
      af3[mf] = *(const bf16x8*)(bufA + d * 64 + (((s*4+lq) ^ (d & 7)) * 8));
    }
#pragma unroll
    for (int nf = 0; nf < 8; nf++) {
      int jj = w * 128 + nf * 16 + lr;
      bf16x8 b3 = *(const bf16x8*)((bf16*)bufB + jj * 64 + (((s*4+lq) ^ (jj & 7)) * 8));
#pragma unroll
      for (int mf = 0; mf < 4; mf++)
        acc3[mf][nf] = __builtin_amdgcn_mfma_f32_16x16x32_bf16(
            af3[mf], b3, acc3[mf][nf], 0, 0, 0);
    }
  }
  bf16* zbase = ZT + (size_t)tb * 262144 + 64*h;
#pragma unroll
  for (int nf = 0; nf < 8; nf++) {
    int jj = w * 128 + nf * 16 + lr;
#pragma unroll
    for (int mf = 0; mf < 4; mf++) {
      bf16x4 o;
#pragma unroll
      for (int r = 0; r < 4; r++) o[r] = (bf16)acc3[mf][nf][r];
      *(bf16x4*)(zbase + (size_t)jj * 512 + mf * 16 + lq * 4) = o;
    }
  }
}

// ---- cvec[tb][j] = bp'[j] + sum_D ZT[tb][j][D] * bq'[D] ----
__global__ __launch_bounds__(512)
void cveck(const bf16* __restrict__ ZT, const float* __restrict__ BS,
           float* __restrict__ cvec) {
  const int tb = blockIdx.x, j = threadIdx.x;
  __shared__ float bq[512];
  bq[j] = BS[j];
  __syncthreads();
  const bf16* zrow = ZT + (size_t)tb * 262144 + (size_t)j * 512;
  float acc = BS[1536 + j];
  for (int d = 0; d < 512; d += 8) {
    bf16x8 zv = *(const bf16x8*)(zrow + d);
#pragma unroll
    for (int i = 0; i < 8; i++) acc += (float)zv[i] * bq[d + i];
  }
  cvec[tb * 512 + j] = acc;
}

extern "C" void kernel_launch(void* const* d_in, const int* in_sizes, int n_in,
                              void* d_out, int out_size, void* d_ws, size_t ws_size,
                              hipStream_t stream) {
  const float* x = (const float*)d_in[0];
  char* ws = (char*)d_ws;
  bf16*  xb    = (bf16*)(ws + 0);             // [32][1024][512]
  bf16*  xT    = (bf16*)(ws + 33554432);      // [32][512][1024]
  bf16*  Gb    = (bf16*)(ws + 67108864);      // [32][512][512]
  bf16*  ZT    = (bf16*)(ws + 83886080);      // [32][512][512]
  bf16*  VT    = (bf16*)(ws + 100663296);     // [32][512][512]
  bf16*  WB    = (bf16*)(ws + 117440512);     // [4][512][512]
  bf16*  WqT   = (bf16*)(ws + 119537664);     // [512][512]
  float* BS    = (float*)(ws + 120061952);    // [4][512]
  float* sv    = (float*)(ws + 120070144);    // [32][512]
  float* ksv   = (float*)(ws + 120135680);    // [2][32][512]
  float* cvec  = (float*)(ws + 120266752);    // [32][512]
  float* spart = (float*)(ws + 120332288);    // [32*8*16][64]
  (void)in_sizes; (void)n_in; (void)out_size; (void)ws_size;

  for (int mat = 0; mat < 4; mat++) {
    const float* W    = (const float*)d_in[1 + 6 * mat + 0];
    const float* bb   = (const float*)d_in[1 + 6 * mat + 1];
    const float* gg   = (const float*)d_in[1 + 6 * mat + 2];
    const float* beta = (const float*)d_in[1 + 6 * mat + 3];
    const float* mu   = (const float*)d_in[1 + 6 * mat + 4];
    const float* var  = (const float*)d_in[1 + 6 * mat + 5];
    prep_w<<<512, 256, 0, stream>>>(W, bb, gg, beta, mu, var,
                                    WB + (size_t)mat * 262144, BS + mat * 512);
  }
  prep_wqT<<<64, 256, 0, stream>>>((const float*)d_in[1], (const float*)d_in[3],
                                   (const float*)d_in[6], WqT);
  cvt_x_t<<<4096, 256, 0, stream>>>(x, xb, xT, spart);
  s_fin<<<32, 512, 0, stream>>>(spart, sv);
  // Gram: G[tb] = xT[tb] * xT[tb]^T  (M=N=512, K=1024)
  gemm_b<16, true, false><<<dim3(16, 32), 256, 0, stream>>>(
      xT, 524288, xT, 524288, nullptr, 0, Gb, nullptr, 262144, 4);
  ksvs<<<dim3(32, 2), 512, 0, stream>>>(WB, sv, ksv);
  zchain<<<256, 256, 0, stream>>>(Gb, WB, BS, ksv, ZT);
  // VT[tb] = ZT[tb] * WqT^T  (M=512 j, N=512 c, K=512)
  gemm_b<8, true, false><<<dim3(16, 32), 256, 0, stream>>>(
      ZT, 262144, WqT, 0, nullptr, 0, VT, nullptr, 262144, 4);
  cveck<<<32, 512, 0, stream>>>(ZT, BS, cvec);
  // out[tb] = xb[tb] * VT[tb]^T + cvec[tb]  (M=1024, N=512, K=512, f32 out)
  gemm_b<8, false, true><<<dim3(32, 32), 256, 0, stream>>>(
      xb, 524288, VT, 262144, cvec, 512, nullptr, (float*)d_out, 524288, 4);
}

// Round 4
// 147.666 us; speedup vs baseline: 1.3027x; 1.3027x over previous
//
#include <hip/hip_runtime.h>

#define T_ 4
#define B_ 8
#define N_ 1024
#define C_ 512
#define H_ 8
#define D_ 64
#define M_ (T_*B_*N_)   // 32768 rows
#define TB_ (T_*B_)     // 32

typedef __bf16 bf16;
typedef __bf16 bf16x4 __attribute__((ext_vector_type(4)));
typedef __bf16 bf16x8 __attribute__((ext_vector_type(8)));
typedef float f32x4 __attribute__((ext_vector_type(4)));

__device__ __forceinline__ void gload16(const void* g, void* l) {
  __builtin_amdgcn_global_load_lds(
      (const __attribute__((address_space(1))) void*)g,
      (__attribute__((address_space(3))) void*)l, 16, 0, 0);
}

struct PtrPack { const float* p[24]; };

// ---- fold BN into weights for all 4 mats: W'[d,c]=W[d,c]*s[d], b'=(b-mu)s+beta ----
__global__ __launch_bounds__(256)
void prep_all(PtrPack pk, bf16* __restrict__ WB, float* __restrict__ BS) {
  const int mat = blockIdx.x >> 9, d = blockIdx.x & 511;
  const float* W    = pk.p[6*mat + 0];
  const float* b    = pk.p[6*mat + 1];
  const float* g    = pk.p[6*mat + 2];
  const float* beta = pk.p[6*mat + 3];
  const float* mu   = pk.p[6*mat + 4];
  const float* var  = pk.p[6*mat + 5];
  float s = g[d] * rsqrtf(var[d] + 1e-5f);
  if (threadIdx.x == 0) BS[mat*512 + d] = (b[d] - mu[d]) * s + beta[d];
  bf16* Wout = WB + (size_t)mat * 262144 + (size_t)d * 512;
  for (int c = threadIdx.x; c < 512; c += 256)
    Wout[c] = (bf16)(W[(size_t)d * 512 + c] * s);
}

// ---- WqT[c][d] = Wq[d][c] * sq[d]  (transposed folded Wq) ----
__global__ __launch_bounds__(256)
void prep_wqT(const float* __restrict__ W, const float* __restrict__ g,
              const float* __restrict__ var, bf16* __restrict__ WqT) {
  const int di = blockIdx.x >> 3, ci = blockIdx.x & 7;
  const int t = threadIdx.x;
  __shared__ float lds[64][65];
  const int rgrp = t >> 4, k = t & 15;
#pragma unroll
  for (int p = 0; p < 4; p++) {
    int r = p * 16 + rgrp;
    int d = di * 64 + r;
    float s = g[d] * rsqrtf(var[d] + 1e-5f);
    float4 v = *(const float4*)(W + (size_t)d * 512 + ci * 64 + k * 4);
    lds[r][k*4+0] = v.x * s; lds[r][k*4+1] = v.y * s;
    lds[r][k*4+2] = v.z * s; lds[r][k*4+3] = v.w * s;
  }
  __syncthreads();
#pragma unroll
  for (int p = 0; p < 16; p++) {
    int c = p * 4 + (t >> 6), dd = t & 63;
    WqT[(size_t)(ci*64 + c) * 512 + di*64 + dd] = (bf16)lds[dd][c];
  }
}

// ---- x (f32) -> xb (bf16, [tb][n][c]) + xT (bf16, [tb][c][n]) + col-sum partials ----
__global__ __launch_bounds__(256)
void cvt_x_t(const float* __restrict__ x, bf16* __restrict__ xb,
             bf16* __restrict__ xT, float* __restrict__ spart) {
  const int bid = blockIdx.x;
  const int tb = bid >> 7, nc = (bid >> 3) & 15, cc = bid & 7;
  const int t = threadIdx.x;
  __shared__ float lds[64][65];
  __shared__ float sred[16][64];
  const float* xbase = x + (size_t)tb * 524288 + (size_t)nc * 64 * 512 + cc * 64;
  bf16* xbb = xb + (size_t)tb * 524288 + (size_t)nc * 64 * 512 + cc * 64;
  bf16* xTb = xT + (size_t)tb * 524288 + (size_t)(cc * 64) * 1024 + nc * 64;
  const int rgrp = t >> 4, k = t & 15;
  float s0 = 0, s1 = 0, s2 = 0, s3 = 0;
#pragma unroll
  for (int p = 0; p < 4; p++) {
    int r = p * 16 + rgrp;
    float4 v = *(const float4*)(xbase + (size_t)r * 512 + k * 4);
    bf16x4 o; o[0]=(bf16)v.x; o[1]=(bf16)v.y; o[2]=(bf16)v.z; o[3]=(bf16)v.w;
    *(bf16x4*)(xbb + (size_t)r * 512 + k * 4) = o;
    lds[r][k*4+0]=v.x; lds[r][k*4+1]=v.y; lds[r][k*4+2]=v.z; lds[r][k*4+3]=v.w;
    s0 += v.x; s1 += v.y; s2 += v.z; s3 += v.w;
  }
  sred[rgrp][k*4+0]=s0; sred[rgrp][k*4+1]=s1; sred[rgrp][k*4+2]=s2; sred[rgrp][k*4+3]=s3;
  __syncthreads();
#pragma unroll
  for (int p = 0; p < 16; p++) {
    int c = p * 4 + (t >> 6), n = t & 63;
    xTb[(size_t)c * 1024 + n] = (bf16)lds[n][c];
  }
  if (t < 64) {
    float tot = 0;
#pragma unroll
    for (int rg = 0; rg < 16; rg++) tot += sred[rg][t];
    spart[(size_t)((tb*8 + cc)*16 + nc) * 64 + t] = tot;
  }
}

// ---- finalize column sums: s[tb][c] ----
__global__ __launch_bounds__(512)
void s_fin(const float* __restrict__ spart, float* __restrict__ sv) {
  const int tb = blockIdx.x, c = threadIdx.x;
  const int cc = c >> 6, cl = c & 63;
  float tot = 0;
#pragma unroll
  for (int ncf = 0; ncf < 16; ncf++)
    tot += spart[(size_t)((tb*8 + cc)*16 + ncf) * 64 + cl];
  sv[tb * 512 + c] = tot;
}

// ---- ks/vs: ksv[m][tb][d] = sum_c W'[m][d,c] * s[tb][c]  (m: 0=k,1=v) ----
__global__ __launch_bounds__(512)
void ksvs(const bf16* __restrict__ WB, const float* __restrict__ sv,
          float* __restrict__ ksv) {
  const int tb = blockIdx.x, m = blockIdx.y;
  __shared__ float sl[512];
  sl[threadIdx.x] = sv[tb * 512 + threadIdx.x];
  __syncthreads();
  const bf16* Wrow = WB + (size_t)(m + 1) * 262144 + (size_t)threadIdx.x * 512;
  float acc = 0;
  for (int c = 0; c < 512; c += 8) {
    bf16x8 wv = *(const bf16x8*)(Wrow + c);
#pragma unroll
    for (int i = 0; i < 8; i++) acc += (float)wv[i] * sl[c + i];
  }
  ksv[m * 16384 + tb * 512 + threadIdx.x] = acc;
}

// =====================================================================
// Batched 128x128-tile GEMM, BK=64, chunk-XOR swizzled LDS, gload_lds
// staging.  C[m][j] = sum_k A[m,k]*Bt[j,k].  Flat grid = 32*MT*NT blocks,
// XCD-clustered: all tiles of a batch land on one XCD (bid%8) for L2 reuse.
// =====================================================================
template <int NKT, int MT, int NT, bool BF16OUT, bool HASBIAS>
__global__ __launch_bounds__(256)
void gemm_b(const bf16* __restrict__ Abase, size_t Astr,
            const bf16* __restrict__ Btbase, size_t Btstr,
            const float* __restrict__ biasb, int biasstr,
            bf16* __restrict__ ob, float* __restrict__ of, size_t Ostr) {
  constexpr int K = NKT * 64;
  constexpr int PERB = MT * NT;
  const int bid = blockIdx.x;
  const int xcd = bid & 7, j9 = bid >> 3;
  const int bat = xcd + 8 * (j9 / PERB);
  const int tile = j9 % PERB;
  const int mi = tile / NT, ni = tile % NT;
  const bf16* A = Abase + (size_t)bat * Astr;
  const bf16* Bt = Btbase + (size_t)bat * Btstr;
  const int m0 = mi * 128, n0 = ni * 128;
  __shared__ __align__(16) bf16 As[128][64];
  __shared__ __align__(16) bf16 Bs[128][64];
  const int tid = threadIdx.x, w = tid >> 6, l = tid & 63;
  const int wm = w >> 1, wn = w & 1;
  const int lr = l & 15, lq = l >> 4, l7 = l & 7, lh = l >> 3;
  const int srcc = (l7 ^ lh) * 8;
  f32x4 acc[4][4] = {};
  for (int kt = 0; kt < NKT; kt++) {
#pragma unroll
    for (int i = 0; i < 4; i++) {
      int rb = w * 32 + i * 8;
      gload16(A  + (size_t)(m0 + rb + lh) * K + kt * 64 + srcc, &As[rb][0]);
      gload16(Bt + (size_t)(n0 + rb + lh) * K + kt * 64 + srcc, &Bs[rb][0]);
    }
    __syncthreads();
    bf16x8 af[4][2], bv[4][2];
#pragma unroll
    for (int f = 0; f < 4; f++) {
      int ra = wm * 64 + f * 16 + lr, rb2 = wn * 64 + f * 16 + lr;
#pragma unroll
      for (int s = 0; s < 2; s++) {
        af[f][s] = *(const bf16x8*)&As[ra][((s*4+lq) ^ (ra & 7)) * 8];
        bv[f][s] = *(const bf16x8*)&Bs[rb2][((s*4+lq) ^ (rb2 & 7)) * 8];
      }
    }
#pragma unroll
    for (int mt = 0; mt < 4; mt++)
#pragma unroll
      for (int nt = 0; nt < 4; nt++)
#pragma unroll
        for (int s = 0; s < 2; s++)
          acc[mt][nt] = __builtin_amdgcn_mfma_f32_16x16x32_bf16(
              af[mt][s], bv[nt][s], acc[mt][nt], 0, 0, 0);
    __syncthreads();
  }
  const int ldo = NT * 128;
#pragma unroll
  for (int mt = 0; mt < 4; mt++)
#pragma unroll
    for (int nt = 0; nt < 4; nt++) {
      int j = n0 + wn * 64 + nt * 16 + lr;
      float bj = HASBIAS ? biasb[(size_t)bat * biasstr + j] : 0.f;
      size_t mrow = (size_t)m0 + wm * 64 + mt * 16 + lq * 4;
#pragma unroll
      for (int r = 0; r < 4; r++) {
        if constexpr (BF16OUT)
          ob[(size_t)bat * Ostr + (mrow + r) * ldo + j] = (bf16)(acc[mt][nt][r] + bj);
        else
          of[(size_t)bat * Ostr + (mrow + r) * ldo + j] = acc[mt][nt][r] + bj;
      }
    }
}

// =====================================================================
// kvz: per (tb,h): kv = (KG_h V_h^T + rank-1 bias terms)/N + bk bv^T   (64x64)
//      Z_h = kv * P_h^T (64x512); write ZT[tb][j][64h+d] and per-head
//      cvec partials cpart[tb][h][j] = sum_d Z[d][j]*bq'[64h+d].
// 4 waves. LDS: bufA 64K (KG_h, then f32 partials, then P), bufV 64K (V_h),
// kvb 8K. All chunk-XOR swizzled (verified pattern family).
// =====================================================================
__global__ __launch_bounds__(256)
void kvz(const bf16* __restrict__ KGb, const bf16* __restrict__ WB,
         const float* __restrict__ BS, const float* __restrict__ ksv,
         bf16* __restrict__ ZT, float* __restrict__ cpart) {
  const int gid = blockIdx.x, tb = gid >> 3, h = gid & 7;
  const int t = threadIdx.x, w = t >> 6, l = t & 63;
  const int lr = l & 15, lq = l >> 4;
  __shared__ __align__(16) char lds[65536 + 65536 + 8192];
  bf16* bufA = (bf16*)lds;                  // KG_h [64][512] -> partials -> P [512][64]
  bf16* bufV = (bf16*)(lds + 65536);        // V_h [64][512]
  bf16* kvb  = (bf16*)(lds + 131072);       // [64][64]

  // stage KG_h and V_h (row = 1KB = one wave-instr; src chunk = l ^ (r&7))
#pragma unroll
  for (int i = 0; i < 16; i++) {
    int r = i * 4 + w;
    gload16(KGb + (size_t)tb * 262144 + (size_t)(64*h + r) * 512 + ((l ^ (r & 7)) * 8),
            bufA + r * 512);
    gload16(WB + 2u * 262144 + (size_t)(64*h + r) * 512 + ((l ^ (r & 7)) * 8),
            bufV + r * 512);
  }
  __syncthreads();

  // kv partial: wave w takes K-slice cols [128w, 128w+128)
  f32x4 acc2[4][4] = {};
#pragma unroll
  for (int ks = 0; ks < 4; ks++) {
    int gch = w * 16 + ks * 4 + lq;
    bf16x8 af2[4], bv2[4];
#pragma unroll
    for (int mf = 0; mf < 4; mf++) {
      int d = mf * 16 + lr;
      af2[mf] = *(const bf16x8*)&bufA[d * 512 + ((gch ^ (d & 7)) * 8)];
    }
#pragma unroll
    for (int nf = 0; nf < 4; nf++) {
      int e = nf * 16 + lr;
      bv2[nf] = *(const bf16x8*)&bufV[e * 512 + ((gch ^ (e & 7)) * 8)];
    }
#pragma unroll
    for (int mf = 0; mf < 4; mf++)
#pragma unroll
      for (int nf = 0; nf < 4; nf++)
        acc2[mf][nf] = __builtin_amdgcn_mfma_f32_16x16x32_bf16(
            af2[mf], bv2[nf], acc2[mf][nf], 0, 0, 0);
  }
  __syncthreads();   // KG reads done; reuse bufA for f32 partials

  float* part = (float*)lds + w * 4096;
#pragma unroll
  for (int mf = 0; mf < 4; mf++)
#pragma unroll
    for (int nf = 0; nf < 4; nf++)
#pragma unroll
      for (int r = 0; r < 4; r++) {
        int d = mf * 16 + lq * 4 + r, e = nf * 16 + lr;
        part[d * 64 + e] = acc2[mf][nf][r];
      }
  __syncthreads();
  {
    const float inv = 1.f / 1024.f;
    const float* pb = (const float*)lds;
#pragma unroll
    for (int jj = 0; jj < 16; jj++) {
      int flat = jj * 256 + t, d = flat >> 6, e = flat & 63;
      float s = pb[flat] + pb[4096 + flat] + pb[8192 + flat] + pb[12288 + flat];
      float ksh = ksv[tb * 512 + 64*h + d];
      float vsh = ksv[16384 + tb * 512 + 64*h + e];
      float bkh = BS[512 + 64*h + d];
      float bvh = BS[1024 + 64*h + e];
      float kv = (s + ksh * bvh + bkh * vsh) * inv + bkh * bvh;
      kvb[d * 64 + (((e >> 3) ^ (d & 7)) * 8 + (e & 7))] = (bf16)kv;
    }
  }
  __syncthreads();   // partials read done; reuse bufA for P

  // stage P: P[j][e] = Wp'[j][64h+e], 512 rows x 64 (row = 128B, 8 rows/instr)
#pragma unroll
  for (int i = 0; i < 16; i++) {
    int rb = i * 32 + w * 8;
    int r = rb + (l >> 3);
    gload16(WB + 3u * 262144 + (size_t)r * 512 + 64*h + (((l & 7) ^ (r & 7)) * 8),
            bufA + rb * 64);
  }
  __syncthreads();

  // Z = kv * P^T : wave w takes j-slice [128w, 128w+128)
  f32x4 acc3[4][8] = {};
#pragma unroll
  for (int s = 0; s < 2; s++) {
    bf16x8 af3[4];
#pragma unroll
    for (int mf = 0; mf < 4; mf++) {
      int d = mf * 16 + lr;
      af3[mf] = *(const bf16x8*)&kvb[d * 64 + (((s*4+lq) ^ (d & 7)) * 8)];
    }
#pragma unroll
    for (int nf = 0; nf < 8; nf++) {
      int jj = w * 128 + nf * 16 + lr;
      bf16x8 b3 = *(const bf16x8*)&bufA[jj * 64 + (((s*4+lq) ^ (jj & 7)) * 8)];
#pragma unroll
      for (int mf = 0; mf < 4; mf++)
        acc3[mf][nf] = __builtin_amdgcn_mfma_f32_16x16x32_bf16(
            af3[mf], b3, acc3[mf][nf], 0, 0, 0);
    }
  }

  bf16* zbase = ZT + (size_t)tb * 262144 + 64*h;
#pragma unroll
  for (int nf = 0; nf < 8; nf++) {
    int jj = w * 128 + nf * 16 + lr;
    float cp = 0.f;
#pragma unroll
    for (int mf = 0; mf < 4; mf++) {
      bf16x4 o;
#pragma unroll
      for (int r = 0; r < 4; r++) {
        o[r] = (bf16)acc3[mf][nf][r];
        cp += acc3[mf][nf][r] * BS[64*h + mf*16 + lq*4 + r];
      }
      *(bf16x4*)(zbase + (size_t)jj * 512 + mf * 16 + lq * 4) = o;
    }
    cp += __shfl_xor(cp, 16);
    cp += __shfl_xor(cp, 32);
    if (lq == 0) cpart[(size_t)(tb * 8 + h) * 512 + jj] = cp;
  }
}

// ---- cvec[tb][j] = bp'[j] + sum_h cpart[tb][h][j] ----
__global__ __launch_bounds__(512)
void cvfin(const float* __restrict__ cpart, const float* __restrict__ BS,
           float* __restrict__ cvec) {
  const int tb = blockIdx.x, j = threadIdx.x;
  float s = BS[1536 + j];
#pragma unroll
  for (int h = 0; h < 8; h++) s += cpart[(size_t)(tb * 8 + h) * 512 + j];
  cvec[tb * 512 + j] = s;
}

extern "C" void kernel_launch(void* const* d_in, const int* in_sizes, int n_in,
                              void* d_out, int out_size, void* d_ws, size_t ws_size,
                              hipStream_t stream) {
  const float* x = (const float*)d_in[0];
  char* ws = (char*)d_ws;
  bf16*  xb    = (bf16*)(ws + 0);             // [32][1024][512]
  bf16*  xT    = (bf16*)(ws + 33554432);      // [32][512][1024]
  bf16*  Gb    = (bf16*)(ws + 67108864);      // [32][512][512]
  bf16*  KGb   = (bf16*)(ws + 83886080);      // [32][512][512]
  bf16*  ZT    = (bf16*)(ws + 100663296);     // [32][512][512]
  bf16*  VT    = (bf16*)(ws + 117440512);     // [32][512][512]
  bf16*  WB    = (bf16*)(ws + 134217728);     // [4][512][512]
  bf16*  WqT   = (bf16*)(ws + 136314880);     // [512][512]
  float* BS    = (float*)(ws + 136839168);    // [4][512]
  float* sv    = (float*)(ws + 136847360);    // [32][512]
  float* ksv   = (float*)(ws + 136912896);    // [2][32][512]
  float* cvec  = (float*)(ws + 137041920);    // [32][512]
  float* cpart = (float*)(ws + 137107456);    // [32][8][512]
  float* spart = (float*)(ws + 137631744);    // [32*8*16][64]
  (void)in_sizes; (void)n_in; (void)out_size; (void)ws_size;

  PtrPack pk;
  for (int i = 0; i < 24; i++) pk.p[i] = (const float*)d_in[1 + i];

  prep_all<<<2048, 256, 0, stream>>>(pk, WB, BS);
  prep_wqT<<<64, 256, 0, stream>>>((const float*)d_in[1], (const float*)d_in[3],
                                   (const float*)d_in[6], WqT);
  cvt_x_t<<<4096, 256, 0, stream>>>(x, xb, xT, spart);
  s_fin<<<32, 512, 0, stream>>>(spart, sv);
  ksvs<<<dim3(32, 2), 512, 0, stream>>>(WB, sv, ksv);
  // Gram: G[tb] = xT[tb] * xT[tb]^T  (M=N=512, K=1024)
  gemm_b<16, 4, 4, true, false><<<512, 256, 0, stream>>>(
      xT, 524288, xT, 524288, nullptr, 0, Gb, nullptr, 262144);
  // KG[tb] = K' * G[tb]   (A shared, G symmetric so Bt=G works)
  gemm_b<8, 4, 4, true, false><<<512, 256, 0, stream>>>(
      WB + 262144, 0, Gb, 262144, nullptr, 0, KGb, nullptr, 262144);
  kvz<<<256, 256, 0, stream>>>(KGb, WB, BS, ksv, ZT, cpart);
  cvfin<<<32, 512, 0, stream>>>(cpart, BS, cvec);
  // VT[tb] = ZT[tb] * WqT^T  (Bt shared)
  gemm_b<8, 4, 4, true, false><<<512, 256, 0, stream>>>(
      ZT, 262144, WqT, 0, nullptr, 0, VT, nullptr, 262144);
  // out[tb] = xb[tb] * VT[tb]^T + cvec[tb]  (f32 out)
  gemm_b<8, 8, 4, false, true><<<1024, 256, 0, stream>>>(
      xb, 524288, VT, 262144, cvec, 512, nullptr, (float*)d_out, 524288);
}